// Round 8
// baseline (148.708 us; speedup 1.0000x reference)
//
#include <hip/hip_runtime.h>
#include <hip/hip_bf16.h>

// (B,T,E,H) = (4, 2048, 1024, 64); scale = E^-0.5 = 1/32.
// Ground truth (r7 pass): inputs fp32, output fp32. ws >= 268 MB.
constexpr int Bc = 4;
constexpr int Tc = 2048;
constexpr int Ec = 1024;
constexpr int Hc = 64;
constexpr float SCALE  = 0.03125f;    // 1/sqrt(1024)
constexpr float M_INIT = -30000.0f;
constexpr float MASK_S = -1.0e8f;

typedef short  short8  __attribute__((ext_vector_type(8)));
typedef float  floatx4 __attribute__((ext_vector_type(4)));

__device__ __forceinline__ unsigned short f2bf(float f) {  // RNE
    union { float f; unsigned int i; } x;
    x.f = f;
    unsigned int r = x.i + 0x7fffu + ((x.i >> 16) & 1u);
    return (unsigned short)(r >> 16);
}
__device__ __forceinline__ short8 pack8(float4 f0, float4 f1) {
    short8 v;
    v[0] = (short)f2bf(f0.x); v[1] = (short)f2bf(f0.y);
    v[2] = (short)f2bf(f0.z); v[3] = (short)f2bf(f0.w);
    v[4] = (short)f2bf(f1.x); v[5] = (short)f2bf(f1.y);
    v[6] = (short)f2bf(f1.z); v[7] = (short)f2bf(f1.w);
    return v;
}

// ---------------------------------------------------------------------------
// Kernel 0: prep. Blocks [0,4096): X fp32 -> Xb bf16 (8 elems/thread).
// Blocks [4096,4288): W fp32 [E][H] -> Wt bf16 [H][E] x3 (r7-proven mapping).
// Memory-bound: ~60 MB traffic ≈ 10 µs.
// ---------------------------------------------------------------------------
__global__ __launch_bounds__(256) void prep(
    const float* __restrict__ X,  const float* __restrict__ Wq,
    const float* __restrict__ Wk, const float* __restrict__ Wv,
    unsigned short* __restrict__ Xb, unsigned short* __restrict__ Wt)
{
    const int bx = blockIdx.x;
    if (bx < 4096) {
        const int idx0 = bx * 2048 + threadIdx.x * 8;
        const float4 f0 = *(const float4*)(X + idx0);
        const float4 f1 = *(const float4*)(X + idx0 + 4);
        *(short8*)(Xb + idx0) = pack8(f0, f1);
    } else {
        const int wb = bx - 4096;            // 0..191
        const int which = wb >> 6;
        const float* W = which == 0 ? Wq : (which == 1 ? Wk : Wv);
        unsigned short* D = Wt + (size_t)which * (Ec * Hc);
        const int i0 = (wb & 63) * 1024 + threadIdx.x * 4;
        const float4 f = *(const float4*)(W + i0);
        const float v[4] = {f.x, f.y, f.z, f.w};
        #pragma unroll
        for (int j = 0; j < 4; ++j) {
            const int i = i0 + j;            // i = e*64 + h
            D[(i & 63) * Ec + (i >> 6)] = f2bf(v[j]);
        }
    }
}

// ---------------------------------------------------------------------------
// Kernel 1: QKV projection, MFMA 16x16x32 bf16 — no LDS, pure load+MFMA.
// Grid (128, 3): x = 64-row tile, y = matrix. Wave w owns 16 rows (1 m-frag
// x 4 n-frags). A-frags from Xb, B-frags from Wt (16 B/lane contiguous).
// which==2 (V) writes V TRANSPOSED to Vt[b][h][t] (attn B-frag layout).
// Sanitizer sentinel 11111 = "qkv MFMA garbage".
// ---------------------------------------------------------------------------
__global__ __launch_bounds__(256) void qkv_mfma4(
    const unsigned short* __restrict__ Xb, const unsigned short* __restrict__ Wt,
    unsigned short* __restrict__ Qo, unsigned short* __restrict__ Ko,
    unsigned short* __restrict__ Vt)
{
    const int tid  = threadIdx.x;
    const int wv   = tid >> 6;
    const int lane = tid & 63;
    const int quad = lane >> 4;
    const int l16  = lane & 15;
    const int which = blockIdx.y;
    const unsigned short* Wm = Wt + (size_t)which * (Ec * Hc);
    const size_t row0 = (size_t)blockIdx.x * 64 + wv * 16;   // global row

    floatx4 acc[4];
    #pragma unroll
    for (int ni = 0; ni < 4; ++ni)
        #pragma unroll
        for (int r = 0; r < 4; ++r) acc[ni][r] = 0.f;

    const unsigned short* xr  = Xb + (row0 + l16) * Ec + quad * 8;
    const unsigned short* wb0 = Wm + (0  + l16) * Ec + quad * 8;
    const unsigned short* wb1 = Wm + (16 + l16) * Ec + quad * 8;
    const unsigned short* wb2 = Wm + (32 + l16) * Ec + quad * 8;
    const unsigned short* wb3 = Wm + (48 + l16) * Ec + quad * 8;

    for (int k0 = 0; k0 < Ec; k0 += 32) {
        const short8 a  = *(const short8*)(xr  + k0);
        const short8 b0 = *(const short8*)(wb0 + k0);
        const short8 b1 = *(const short8*)(wb1 + k0);
        const short8 b2 = *(const short8*)(wb2 + k0);
        const short8 b3 = *(const short8*)(wb3 + k0);
        acc[0] = __builtin_amdgcn_mfma_f32_16x16x32_bf16(a, b0, acc[0], 0, 0, 0);
        acc[1] = __builtin_amdgcn_mfma_f32_16x16x32_bf16(a, b1, acc[1], 0, 0, 0);
        acc[2] = __builtin_amdgcn_mfma_f32_16x16x32_bf16(a, b2, acc[2], 0, 0, 0);
        acc[3] = __builtin_amdgcn_mfma_f32_16x16x32_bf16(a, b3, acc[3], 0, 0, 0);
    }

    // C/D layout: col = lane&15, row = quad*4 + reg (verified m89/m91 + r7).
    if (which < 2) {
        unsigned short* O = which == 0 ? Qo : Ko;
        #pragma unroll
        for (int ni = 0; ni < 4; ++ni)
            #pragma unroll
            for (int r = 0; r < 4; ++r) {
                float x = acc[ni][r];
                if (!(x > -1.0e4f && x < 1.0e4f)) x = 11111.0f;
                O[(row0 + quad * 4 + r) * Hc + 16 * ni + l16] = f2bf(x);
            }
    } else {
        // V^T: Vt[b][h][t], b = row0/2048, t = row % 2048. 4 consecutive t
        // per (ni) -> one 8 B store.
        const size_t b  = row0 >> 11;
        const int    t0 = (int)(row0 & 2047) + quad * 4;
        unsigned short* VtB = Vt + b * ((size_t)Hc * Tc);
        #pragma unroll
        for (int ni = 0; ni < 4; ++ni) {
            unsigned int pk[2];
            #pragma unroll
            for (int half = 0; half < 2; ++half) {
                float x0 = acc[ni][half * 2 + 0], x1 = acc[ni][half * 2 + 1];
                if (!(x0 > -1.0e4f && x0 < 1.0e4f)) x0 = 11111.0f;
                if (!(x1 > -1.0e4f && x1 < 1.0e4f)) x1 = 11111.0f;
                pk[half] = (unsigned int)f2bf(x0) | ((unsigned int)f2bf(x1) << 16);
            }
            uint2 st; st.x = pk[0]; st.y = pk[1];
            *(uint2*)(VtB + (size_t)(16 * ni + l16) * Tc + t0) = st;
        }
    }
}

// ---------------------------------------------------------------------------
// Kernel 2: causal flash attention, MFMA 16x16x32 bf16 — ZERO barriers in the
// k-loop. Grid (128, 4), qt reversed (heavy blocks first). Wave w owns
// k-tiles kb = 64w + 256j with private online-softmax state. K B-frags and
// V^T B-frags straight from global (16 B/lane contiguous). P round-trips
// through wave-private LDS (r7-proven). 4-way merge at end. Sentinel 555.
// ---------------------------------------------------------------------------
__global__ __launch_bounds__(256) void attn_mfma3(
    const unsigned short* __restrict__ Q, const unsigned short* __restrict__ K,
    const unsigned short* __restrict__ Vt, float* __restrict__ Out)
{
    __shared__ __align__(16) unsigned short Pb[4][16][72];   // 9.2 KB
    __shared__ __align__(16) float accS[4][16][64];          // 16 KB

    const int tid  = threadIdx.x;
    const int wv   = tid >> 6;
    const int lane = tid & 63;
    const int quad = lane >> 4;
    const int l16  = lane & 15;
    const int qt   = 127 - blockIdx.x;    // reversed: heavy first
    const int b    = blockIdx.y;
    const int qend = qt * 16 + 16;
    const size_t base = (size_t)b * Tc * Hc;
    const unsigned short* VtB = Vt + (size_t)b * Hc * Tc;

    short8 aQ[2];
    #pragma unroll
    for (int ks = 0; ks < 2; ++ks)
        aQ[ks] = *(const short8*)(Q + base + (size_t)(qt * 16 + l16) * Hc + ks * 32 + quad * 8);

    floatx4 acc[4];
    float m_st[4], l_st[4];
    #pragma unroll
    for (int nh = 0; nh < 4; ++nh)
        #pragma unroll
        for (int r = 0; r < 4; ++r) acc[nh][r] = 0.f;
    #pragma unroll
    for (int r = 0; r < 4; ++r) { m_st[r] = M_INIT; l_st[r] = 0.f; }

    for (int kb = wv * 64; kb < qend; kb += 256) {
        // ---- S = Q K^T (16 x 64), K B-frags from global ----
        floatx4 s[4];
        #pragma unroll
        for (int ni = 0; ni < 4; ++ni)
            #pragma unroll
            for (int r = 0; r < 4; ++r) s[ni][r] = 0.f;
        #pragma unroll
        for (int ks = 0; ks < 2; ++ks) {
            short8 bk[4];
            #pragma unroll
            for (int ni = 0; ni < 4; ++ni)
                bk[ni] = *(const short8*)(K + base +
                    (size_t)(kb + 16 * ni + l16) * Hc + ks * 32 + quad * 8);
            #pragma unroll
            for (int ni = 0; ni < 4; ++ni)
                s[ni] = __builtin_amdgcn_mfma_f32_16x16x32_bf16(aQ[ks], bk[ni], s[ni], 0, 0, 0);
        }

        // ---- mask + online softmax (rows = quad*4+r, cols = l16) ----
        float alpha[4];
        #pragma unroll
        for (int r = 0; r < 4; ++r) {
            const int qrow = qt * 16 + quad * 4 + r;
            float mr = MASK_S;
            #pragma unroll
            for (int ni = 0; ni < 4; ++ni) {
                const int kcol = kb + 16 * ni + l16;
                float v = s[ni][r] * SCALE;
                if (kcol > qrow) v = MASK_S;
                s[ni][r] = v;
                mr = fmaxf(mr, v);
            }
            mr = fmaxf(mr, __shfl_xor(mr, 1));
            mr = fmaxf(mr, __shfl_xor(mr, 2));
            mr = fmaxf(mr, __shfl_xor(mr, 4));
            mr = fmaxf(mr, __shfl_xor(mr, 8));
            const float mnew = fmaxf(m_st[r], mr);
            alpha[r] = __expf(m_st[r] - mnew);
            m_st[r] = mnew;
            float sum = 0.f;
            #pragma unroll
            for (int ni = 0; ni < 4; ++ni) {
                const float p = __expf(s[ni][r] - mnew);
                s[ni][r] = p;
                sum += p;
            }
            sum += __shfl_xor(sum, 1);
            sum += __shfl_xor(sum, 2);
            sum += __shfl_xor(sum, 4);
            sum += __shfl_xor(sum, 8);
            l_st[r] = l_st[r] * alpha[r] + sum;
        }
        #pragma unroll
        for (int ni = 0; ni < 4; ++ni)
            #pragma unroll
            for (int r = 0; r < 4; ++r) {
                acc[ni][r] *= alpha[r];
                Pb[wv][quad * 4 + r][16 * ni + l16] = f2bf(s[ni][r]);
            }

        // ---- O += P V : P A-frags (wave-private LDS), V^T B-frags global ----
        #pragma unroll
        for (int ks = 0; ks < 2; ++ks) {
            const short8 aP = *(const short8*)&Pb[wv][l16][ks * 32 + quad * 8];
            short8 bv[4];
            #pragma unroll
            for (int nh = 0; nh < 4; ++nh)
                bv[nh] = *(const short8*)(VtB +
                    (size_t)(16 * nh + l16) * Tc + kb + ks * 32 + quad * 8);
            #pragma unroll
            for (int nh = 0; nh < 4; ++nh)
                acc[nh] = __builtin_amdgcn_mfma_f32_16x16x32_bf16(aP, bv[nh], acc[nh], 0, 0, 0);
        }
    }

    // ---- merge the 4 per-wave states (r7-proven) ----
    __syncthreads();                      // all waves done with their Pb
    float* mlS = (float*)&Pb[0][0][0];    // 4 x 16 x {m,l}
    #pragma unroll
    for (int nh = 0; nh < 4; ++nh)
        #pragma unroll
        for (int r = 0; r < 4; ++r)
            accS[wv][quad * 4 + r][16 * nh + l16] = acc[nh][r];
    if (l16 == 0) {
        #pragma unroll
        for (int r = 0; r < 4; ++r) {
            const int row = quad * 4 + r;
            mlS[(wv * 16 + row) * 2 + 0] = m_st[r];
            mlS[(wv * 16 + row) * 2 + 1] = l_st[r];
        }
    }
    __syncthreads();
    {
        const int q  = tid >> 4;          // 0..15
        const int h0 = (tid & 15) * 4;    // 0..60
        float mw[4], lw[4], M = -3.4e38f;
        #pragma unroll
        for (int w = 0; w < 4; ++w) {
            mw[w] = mlS[(w * 16 + q) * 2 + 0];
            lw[w] = mlS[(w * 16 + q) * 2 + 1];
            M = fmaxf(M, mw[w]);
        }
        float coef[4], denom = 0.f;
        #pragma unroll
        for (int w = 0; w < 4; ++w) {
            coef[w] = __expf(mw[w] - M);
            denom += coef[w] * lw[w];
        }
        const float inv = 1.f / denom;
        float4 st;
        float* sp = &st.x;
        #pragma unroll
        for (int j = 0; j < 4; ++j) {
            float o = 0.f;
            #pragma unroll
            for (int w = 0; w < 4; ++w)
                o += coef[w] * accS[w][q][h0 + j];
            o *= inv;
            if (!(o > -1.0e5f && o < 1.0e5f)) o = 555.0f;   // diagnostic
            sp[j] = o;
        }
        *(float4*)(Out + base + (size_t)(qt * 16 + q) * Hc + h0) = st;
    }
}

extern "C" void kernel_launch(void* const* d_in, const int* in_sizes, int n_in,
                              void* d_out, int out_size, void* d_ws, size_t ws_size,
                              hipStream_t stream)
{
    const float* X  = (const float*)d_in[0];
    const float* Wq = (const float*)d_in[1];
    const float* Wk = (const float*)d_in[2];
    const float* Wv = (const float*)d_in[3];

    const size_t NX = (size_t)Bc * Tc * Ec;   // 8,388,608
    const size_t N  = (size_t)Bc * Tc * Hc;   //   524,288

    unsigned short* Xb  = (unsigned short*)d_ws;   // 16 MB bf16 X
    unsigned short* Wt  = Xb + NX;                 // 384 KB bf16 W^T x3
    unsigned short* Qws = Wt + 3 * (size_t)Ec * Hc;// 1 MB
    unsigned short* Kws = Qws + N;                 // 1 MB
    unsigned short* Vtw = Kws + N;                 // 1 MB (V transposed [b][h][t])

    prep<<<dim3(4288), dim3(256), 0, stream>>>(X, Wq, Wk, Wv, Xb, Wt);
    qkv_mfma4<<<dim3(128, 3), dim3(256), 0, stream>>>(Xb, Wt, Qws, Kws, Vtw);
    attn_mfma3<<<dim3(128, 4), dim3(256), 0, stream>>>(
        Qws, Kws, Vtw, (float*)d_out);
}